// Round 13
// baseline (146.604 us; speedup 1.0000x reference)
//
#include <hip/hip_runtime.h>
#include <hip/hip_bf16.h>

#define NN 8192
#define F 64
#define ALPHA 0.2f
#define L2E 1.44269504f
#define DBOUND 16.0f
#define G 8
#define COLS (NN / G)        // 1024
#define NSTEPS (COLS / 32)   // 32
#define NCHUNK 4             // 4 chunks x 256 cols

typedef __attribute__((ext_vector_type(8))) short short8;
typedef __attribute__((ext_vector_type(4))) float f32x4;
typedef __attribute__((ext_vector_type(4))) int i32x4;

__device__ __forceinline__ unsigned fb(float x) {
    return __builtin_bit_cast(unsigned, x);
}
__device__ __forceinline__ short f2bf(float x) {
    union { float f; unsigned u; } v; v.f = x;
    unsigned r = v.u + 0x7FFF + ((v.u >> 16) & 1);
    return (short)(r >> 16);
}

// Kernel A: Wh = h @ W^T (fp32), store WhT (bf16, transposed 64 x 8192),
// src = Wh@a1 (raw), dst2 = (Wh@a2) * log2(e).
__global__ __launch_bounds__(256) void k_prep(const float* __restrict__ h,
        const float* __restrict__ W, const float* __restrict__ a,
        short* __restrict__ WhT, float* __restrict__ src, float* __restrict__ dst2) {
    __shared__ float Wl[F][F + 1];
    __shared__ short shT[F][4];
    int tid = threadIdx.x;
    for (int m = 0; m < 4; ++m) {
        int idx = m * 1024 + tid * 4;
        float4 v = *(const float4*)&W[idx];
        int row = idx >> 6, col = idx & 63;
        Wl[row][col] = v.x; Wl[row][col + 1] = v.y;
        Wl[row][col + 2] = v.z; Wl[row][col + 3] = v.w;
    }
    __syncthreads();
    int w = tid >> 6, lane = tid & 63;
    int i = blockIdx.x * 4 + w;
    const float* hrow = &h[(size_t)i * F];
    float wh = 0.f;
    #pragma unroll
    for (int k = 0; k < F; k += 4) {
        float4 hv = *(const float4*)&hrow[k];
        wh += hv.x * Wl[lane][k] + hv.y * Wl[lane][k + 1]
            + hv.z * Wl[lane][k + 2] + hv.w * Wl[lane][k + 3];
    }
    shT[lane][w] = f2bf(wh);
    float s1 = wh * a[lane];
    float s2 = wh * a[F + lane];
    #pragma unroll
    for (int off = 32; off; off >>= 1) {
        s1 += __shfl_xor(s1, off);
        s2 += __shfl_xor(s2, off);
    }
    if (lane == 0) { src[i] = s1; dst2[i] = s2 * L2E; }
    __syncthreads();
    if (tid < F) {
        short4 v = make_short4(shT[tid][0], shT[tid][1], shT[tid][2], shT[tid][3]);
        *(short4*)&WhT[(size_t)tid * NN + blockIdx.x * 4] = v;
    }
}

// Kernel P: repack WhT [64][8192] into MFMA-fragment order.
__global__ __launch_bounds__(256) void k_pack(const short* __restrict__ WhT,
                                              short* __restrict__ WhTt) {
    int tid = blockIdx.x * 256 + threadIdx.x;   // 65536 threads
    int lp = tid & 63;
    int f  = (tid >> 6) & 3;
    int t  = tid >> 8;
    int row = f * 16 + (lp & 15);
    int col = t * 32 + ((lp >> 4) << 3);
    short8 v = *(const short8*)&WhT[(size_t)row * NN + col];
    *(short8*)&WhTt[(size_t)tid * 8] = v;
}

// Kernel B: fused attention with PRODUCER/CONSUMER WAVE SPECIALIZATION.
// 512 threads: waves 0-3 stream adj (wave-linear 1KB NT loads) -> bitmask
// into double-buffered LDS; waves 4-7 run the R10 compute loop. One barrier
// per 256-col chunk; producers stage chunk c+1 while consumers compute c.
__global__ __launch_bounds__(512, 4) void k_attn(const int* __restrict__ adj,
        const short8* __restrict__ WhTt, const float* __restrict__ src,
        const float* __restrict__ dst2,
        float* __restrict__ Opart, float* __restrict__ lpart) {
    __shared__ unsigned mlds[2][64][9];   // [buf][row][8 dwords + pad]
    __shared__ float dlds[COLS];          // dst2 slice

    int rb = blockIdx.x / G;
    int g  = blockIdx.x % G;
    int jbase = g * COLS;
    int tid = threadIdx.x;
    int w = tid >> 6, lane = tid & 63;

    for (int idx = tid; idx < COLS; idx += 512)
        dlds[idx] = dst2[jbase + idx];

    const int* abase = adj + (size_t)(rb * 64) * NN + jbase;
    int sh8 = 4 * (lane & 7);
    bool producer = (w < 4);

    // Producer wave w stages rows w*16..w*16+15 of chunk c into mlds[c&1].
#define STG1(rr, c, buf) { \
    i32x4 av = __builtin_nontemporal_load( \
        (const i32x4*)(abase + (size_t)(rr) * NN + (c) * 256) + lane); \
    unsigned n = (av.x > 0 ? 1u : 0u) | (av.y > 0 ? 2u : 0u) \
               | (av.z > 0 ? 4u : 0u) | (av.w > 0 ? 8u : 0u); \
    unsigned v = n << sh8; \
    v |= __shfl_xor(v, 1); v |= __shfl_xor(v, 2); v |= __shfl_xor(v, 4); \
    if ((lane & 7) == 0) mlds[buf][rr][lane >> 3] = v; }

#define STAGE(c) { int _b = (c) & 1; int _r0 = w * 16; \
    STG1(_r0,      c, _b) STG1(_r0 + 1,  c, _b) STG1(_r0 + 2,  c, _b) STG1(_r0 + 3,  c, _b) \
    STG1(_r0 + 4,  c, _b) STG1(_r0 + 5,  c, _b) STG1(_r0 + 6,  c, _b) STG1(_r0 + 7,  c, _b) \
    STG1(_r0 + 8,  c, _b) STG1(_r0 + 9,  c, _b) STG1(_r0 + 10, c, _b) STG1(_r0 + 11, c, _b) \
    STG1(_r0 + 12, c, _b) STG1(_r0 + 13, c, _b) STG1(_r0 + 14, c, _b) STG1(_r0 + 15, c, _b) }

    int cw = w & 3;                       // consumer wave index 0..3
    int r = lane & 15, q = lane >> 4;
    int qs = q * 8;
    int i = rb * 64 + cw * 16 + r;

    float srcv = producer ? 0.f : src[i];
    float sM = srcv + DBOUND;
    float Mi = fmaxf(sM, ALPHA * sM);
    float sL  = srcv * L2E;
    float MiL = Mi * L2E;
    float C1 = sL - MiL;
    float C2 = fmaf(sL, ALPHA, -MiL);

    f32x4 acc0{}, acc1{}, acc2{}, acc3{}, acc4{};
    short8 ones;
    #pragma unroll
    for (int k = 0; k < 8; ++k) ones[k] = (short)0x3F80;  // bf16 1.0

#define LDB(tt, B0, B1, B2, B3) { \
    const short8* bp = WhTt + (size_t)(g * 32 + (tt)) * 256; \
    B0 = bp[lane]; B1 = bp[64 + lane]; B2 = bp[128 + lane]; B3 = bp[192 + lane]; }

#define PEL(dv, bit, eo) { \
    float t1 = (dv) + C1; \
    float t2 = fmaf((dv), ALPHA, C2); \
    float e = __builtin_amdgcn_exp2f(fmaxf(t1, t2)); \
    eo = (bit) ? e : 0.0f; }

    short8 cb0, cb1, cb2, cb3, nb0, nb1, nb2, nb3;
    if (producer) {
        STAGE(0)
    } else {
        LDB(0, cb0, cb1, cb2, cb3)
    }
    __syncthreads();

    for (int c = 0; c < NCHUNK; ++c) {
        if (producer) {
            if (c + 1 < NCHUNK) STAGE(c + 1)      // fills mlds[(c+1)&1]
        } else {
            const unsigned* mrow = &mlds[c & 1][cw * 16 + r][0];
            #pragma unroll
            for (int ts = 0; ts < 8; ++ts) {
                int t = c * 8 + ts;
                int tn = (t + 1 < NSTEPS) ? t + 1 : t;
                LDB(tn, nb0, nb1, nb2, nb3)       // in flight over this step

                unsigned m8 = (mrow[ts] >> qs) & 0xffu;
                float4 d0 = *(const float4*)&dlds[t * 32 + qs];
                float4 d1 = *(const float4*)&dlds[t * 32 + qs + 4];

                float e0, e1, e2, e3, e4, e5, e6, e7;
                PEL(d0.x, (m8 & 1u),   e0) PEL(d0.y, (m8 & 2u),   e1)
                PEL(d0.z, (m8 & 4u),   e2) PEL(d0.w, (m8 & 8u),   e3)
                PEL(d1.x, (m8 & 16u),  e4) PEL(d1.y, (m8 & 32u),  e5)
                PEL(d1.z, (m8 & 64u),  e6) PEL(d1.w, (m8 & 128u), e7)

                unsigned w0 = __builtin_amdgcn_perm(fb(e1), fb(e0), 0x07060302u);
                unsigned w1 = __builtin_amdgcn_perm(fb(e3), fb(e2), 0x07060302u);
                unsigned w2 = __builtin_amdgcn_perm(fb(e5), fb(e4), 0x07060302u);
                unsigned w3 = __builtin_amdgcn_perm(fb(e7), fb(e6), 0x07060302u);
                short8 af = __builtin_bit_cast(short8, make_uint4(w0, w1, w2, w3));

                acc0 = __builtin_amdgcn_mfma_f32_16x16x32_bf16(af, cb0, acc0, 0, 0, 0);
                acc1 = __builtin_amdgcn_mfma_f32_16x16x32_bf16(af, cb1, acc1, 0, 0, 0);
                acc2 = __builtin_amdgcn_mfma_f32_16x16x32_bf16(af, cb2, acc2, 0, 0, 0);
                acc3 = __builtin_amdgcn_mfma_f32_16x16x32_bf16(af, cb3, acc3, 0, 0, 0);
                acc4 = __builtin_amdgcn_mfma_f32_16x16x32_bf16(af, ones, acc4, 0, 0, 0);

                cb0 = nb0; cb1 = nb1; cb2 = nb2; cb3 = nb3;
            }
        }
        __syncthreads();
    }
#undef PEL
#undef LDB
#undef STAGE
#undef STG1

    if (producer) return;

    // acc4: every column holds the row-sum; C rows = q*4 + reg.
    int ic = rb * 64 + cw * 16 + q * 4;
    if (r == 0) {
        #pragma unroll
        for (int reg = 0; reg < 4; ++reg)
            lpart[(size_t)g * NN + ic + reg] = acc4[reg];
    }

    size_t ob = (size_t)g * (size_t)(NN * F);
    #pragma unroll
    for (int reg = 0; reg < 4; ++reg) {
        size_t ro = ob + (size_t)(ic + reg) * F + r;
        Opart[ro]      = acc0[reg];
        Opart[ro + 16] = acc1[reg];
        Opart[ro + 32] = acc2[reg];
        Opart[ro + 48] = acc3[reg];
    }
}

// Kernel D: out = elu( (sum_g Opart) / (sum_g lpart) )
__global__ __launch_bounds__(256) void k_reduce(const float* __restrict__ Opart,
        const float* __restrict__ lpart, float* __restrict__ out) {
    int idx = blockIdx.x * 256 + threadIdx.x;
    int i = idx >> 6;
    float o = 0.f, l = 0.f;
    #pragma unroll
    for (int g = 0; g < G; ++g) {
        o += Opart[(size_t)g * (NN * F) + idx];
        l += lpart[(size_t)g * NN + i];
    }
    float hp = o / l;
    out[idx] = hp > 0.f ? hp : __expf(hp) - 1.f;
}

extern "C" void kernel_launch(void* const* d_in, const int* in_sizes, int n_in,
                              void* d_out, int out_size, void* d_ws, size_t ws_size,
                              hipStream_t stream) {
    const float* h  = (const float*)d_in[0];
    const int* adj  = (const int*)d_in[1];
    const float* W  = (const float*)d_in[2];
    const float* a  = (const float*)d_in[3];
    float* out = (float*)d_out;

    char* ws = (char*)d_ws;
    const size_t OFF_WHT  = 0;                       // 1 MB bf16 WhT
    const size_t OFF_WHTT = (1u << 20);              // 1 MB fragment-order WhTt
    const size_t OFF_SRC  = (2u << 20);              // 32 KB
    const size_t OFF_DST  = OFF_SRC + (32u << 10);   // 32 KB
    const size_t OFF_LP   = OFF_DST + (32u << 10);   // 256 KB (G*NN*4)
    const size_t OFF_OP   = OFF_LP + (size_t)G * NN * 4;      // 16 MB Opart

    short* WhT   = (short*)(ws + OFF_WHT);
    short* WhTt  = (short*)(ws + OFF_WHTT);
    float* src   = (float*)(ws + OFF_SRC);
    float* dst2  = (float*)(ws + OFF_DST);
    float* lpart = (float*)(ws + OFF_LP);
    float* Opart = (float*)(ws + OFF_OP);

    k_prep<<<NN / 4, 256, 0, stream>>>(h, W, a, WhT, src, dst2);
    k_pack<<<256, 256, 0, stream>>>(WhT, WhTt);
    k_attn<<<(NN / 64) * G, 512, 0, stream>>>(adj, (const short8*)WhTt, src, dst2,
                                              Opart, lpart);
    k_reduce<<<(NN * F) / 256, 256, 0, stream>>>(Opart, lpart, out);
}

// Round 14
// 102.321 us; speedup vs baseline: 1.4328x; 1.4328x over previous
//
#include <hip/hip_runtime.h>
#include <hip/hip_bf16.h>

#define NN 8192
#define F 64
#define ALPHA 0.2f
#define L2E 1.44269504f
#define DBOUND 16.0f
#define G 8
#define COLS (NN / G)        // 1024
#define NSTEPS (COLS / 32)   // 32

typedef __attribute__((ext_vector_type(8))) short short8;
typedef __attribute__((ext_vector_type(4))) float f32x4;
typedef __attribute__((ext_vector_type(4))) int i32x4;

__device__ __forceinline__ unsigned fb(float x) {
    return __builtin_bit_cast(unsigned, x);
}
__device__ __forceinline__ short f2bf(float x) {
    union { float f; unsigned u; } v; v.f = x;
    unsigned r = v.u + 0x7FFF + ((v.u >> 16) & 1);
    return (short)(r >> 16);
}

// Kernel 0: MERGED independent producers.
//   blocks [0, 2048):      prep — Wh=h@W^T, WhTt (fragment order, direct),
//                          src, dst2 = (Wh@a2)*log2e
//   blocks [2048, 4096):   mask — adj (256MB) -> bitmask (8MB), wave-linear
//                          16B/lane NT loads (measured 6.2 TB/s)
// No data dependency between halves -> HW co-schedules: HBM-bound mask
// overlaps VALU-bound prep. Runs at ~max(41, 7) us.
__global__ __launch_bounds__(256) void k_fused0(const float* __restrict__ h,
        const float* __restrict__ W, const float* __restrict__ a,
        const int* __restrict__ adj,
        short* __restrict__ WhTt, float* __restrict__ src,
        float* __restrict__ dst2, unsigned long long* __restrict__ mg) {
    __shared__ float Wl[F][F + 1];
    __shared__ short shT[F][4];
    int tid = threadIdx.x;

    if (blockIdx.x >= NN / 4) {
        // ---- mask half ----
        int bid = blockIdx.x - NN / 4;            // 0..2047
        int w = tid >> 6, l = tid & 63;
        int gw = bid * 4 + w;
        const int NW = 2048 * 4;
        const int NCH = (NN * NN) / 256;          // 262144 chunks of 1 KB
        int sh = 4 * (l & 15);
        #pragma unroll 4
        for (int c = gw; c < NCH; c += NW) {
            size_t base = (size_t)c * 256;
            i32x4 av = __builtin_nontemporal_load((const i32x4*)(adj + base) + l);
            unsigned n = (av.x > 0 ? 1u : 0u) | (av.y > 0 ? 2u : 0u)
                       | (av.z > 0 ? 4u : 0u) | (av.w > 0 ? 8u : 0u);
            unsigned long long v = (unsigned long long)n << sh;
            v |= __shfl_xor(v, 1);
            v |= __shfl_xor(v, 2);
            v |= __shfl_xor(v, 4);
            v |= __shfl_xor(v, 8);
            if ((l & 15) == 0)
                mg[base / 64 + (l >> 4)] = v;
        }
        return;
    }

    // ---- prep half (blocks 0..2047) ----
    for (int m = 0; m < 4; ++m) {
        int idx = m * 1024 + tid * 4;
        float4 v = *(const float4*)&W[idx];
        int row = idx >> 6, col = idx & 63;
        Wl[row][col] = v.x; Wl[row][col + 1] = v.y;
        Wl[row][col + 2] = v.z; Wl[row][col + 3] = v.w;
    }
    __syncthreads();
    int w = tid >> 6, lane = tid & 63;
    int i = blockIdx.x * 4 + w;
    const float* hrow = &h[(size_t)i * F];
    float wh = 0.f;
    #pragma unroll
    for (int k = 0; k < F; k += 4) {
        float4 hv = *(const float4*)&hrow[k];
        wh += hv.x * Wl[lane][k] + hv.y * Wl[lane][k + 1]
            + hv.z * Wl[lane][k + 2] + hv.w * Wl[lane][k + 3];
    }
    shT[lane][w] = f2bf(wh);
    float s1 = wh * a[lane];
    float s2 = wh * a[F + lane];
    #pragma unroll
    for (int off = 32; off; off >>= 1) {
        s1 += __shfl_xor(s1, off);
        s2 += __shfl_xor(s2, off);
    }
    if (lane == 0) { src[i] = s1; dst2[i] = s2 * L2E; }
    __syncthreads();
    if (tid < F) {
        // direct fragment-order write (replaces k_pack):
        // elem = ((t*4 + f>>4)*64 + (off>>3)*16 + (f&15))*8 + (off&7)
        int f = tid;
        int b = blockIdx.x;
        int t = b >> 3;
        int off = (b * 4) & 31;
        size_t addr = (((size_t)(t * 4 + (f >> 4)) * 64
                       + (off >> 3) * 16 + (f & 15)) << 3) + (off & 7);
        short4 v = make_short4(shT[f][0], shT[f][1], shT[f][2], shT[f][3]);
        *(short4*)&WhTt[addr] = v;
    }
}

// Kernel B: fused masked-softmax attention (proven R10 structure, 24.4 us).
__global__ __launch_bounds__(256, 4) void k_attn(const unsigned* __restrict__ maskg,
        const short8* __restrict__ WhTt, const float* __restrict__ src,
        const float* __restrict__ dst2,
        float* __restrict__ Opart, float* __restrict__ lpart) {
    __shared__ unsigned mlds[64][33];     // 64 rows x 32 mask dwords (+1 pad)
    __shared__ float dlds[COLS];          // dst2 slice
    __shared__ short8 tbuf[2][256];       // 2 x 4KB B-tile double buffer

    int rb = blockIdx.x / G;
    int g  = blockIdx.x % G;
    int jbase = g * COLS;
    int tid = threadIdx.x;

    for (int idx = tid; idx < 64 * (COLS / 32); idx += 256) {
        int rr = idx >> 5, cc = idx & 31;
        mlds[rr][cc] = maskg[(size_t)(rb * 64 + rr) * (NN / 32) + (jbase >> 5) + cc];
    }
    for (int idx = tid; idx < COLS; idx += 256)
        dlds[idx] = dst2[jbase + idx];

    // prologue: stage tile g*32 into tbuf[0]
    tbuf[0][tid] = WhTt[(size_t)(g * 32) * 256 + tid];

    int w = tid >> 6, lane = tid & 63;
    int r = lane & 15, q = lane >> 4;
    int qs = q * 8;
    int i = rb * 64 + w * 16 + r;

    float srcv = src[i];
    float sM = srcv + DBOUND;
    float Mi = fmaxf(sM, ALPHA * sM);
    float sL  = srcv * L2E;
    float MiL = Mi * L2E;
    float C1 = sL - MiL;
    float C2 = fmaf(sL, ALPHA, -MiL);

    f32x4 acc0{}, acc1{}, acc2{}, acc3{}, acc4{};
    short8 ones;
    #pragma unroll
    for (int k = 0; k < 8; ++k) ones[k] = (short)0x3F80;  // bf16 1.0

    const unsigned* mrow = &mlds[w * 16 + r][0];

#define PEL(dv, bit, eo) { \
    float t1 = (dv) + C1; \
    float t2 = fmaf((dv), ALPHA, C2); \
    float e = __builtin_amdgcn_exp2f(fmaxf(t1, t2)); \
    eo = (bit) ? e : 0.0f; }

    for (int t = 0; t < NSTEPS; ++t) {
        __syncthreads();                          // tbuf[t&1] ready; vmcnt==0 here

        int tn = (t + 1 < NSTEPS) ? t + 1 : t;    // safe dummy on last iter
        short8 nx = WhTt[(size_t)(g * 32 + tn) * 256 + tid];  // in flight over compute

        const short8* bp = &tbuf[t & 1][0];
        short8 b0 = bp[lane];
        short8 b1 = bp[64 + lane];
        short8 b2 = bp[128 + lane];
        short8 b3 = bp[192 + lane];

        unsigned m8 = (mrow[t] >> qs) & 0xffu;
        float4 d0 = *(const float4*)&dlds[t * 32 + qs];
        float4 d1 = *(const float4*)&dlds[t * 32 + qs + 4];

        float e0, e1, e2, e3, e4, e5, e6, e7;
        PEL(d0.x, (m8 & 1u),   e0) PEL(d0.y, (m8 & 2u),   e1)
        PEL(d0.z, (m8 & 4u),   e2) PEL(d0.w, (m8 & 8u),   e3)
        PEL(d1.x, (m8 & 16u),  e4) PEL(d1.y, (m8 & 32u),  e5)
        PEL(d1.z, (m8 & 64u),  e6) PEL(d1.w, (m8 & 128u), e7)

        unsigned w0 = __builtin_amdgcn_perm(fb(e1), fb(e0), 0x07060302u);
        unsigned w1 = __builtin_amdgcn_perm(fb(e3), fb(e2), 0x07060302u);
        unsigned w2 = __builtin_amdgcn_perm(fb(e5), fb(e4), 0x07060302u);
        unsigned w3 = __builtin_amdgcn_perm(fb(e7), fb(e6), 0x07060302u);
        short8 af = __builtin_bit_cast(short8, make_uint4(w0, w1, w2, w3));

        acc0 = __builtin_amdgcn_mfma_f32_16x16x32_bf16(af, b0, acc0, 0, 0, 0);
        acc1 = __builtin_amdgcn_mfma_f32_16x16x32_bf16(af, b1, acc1, 0, 0, 0);
        acc2 = __builtin_amdgcn_mfma_f32_16x16x32_bf16(af, b2, acc2, 0, 0, 0);
        acc3 = __builtin_amdgcn_mfma_f32_16x16x32_bf16(af, b3, acc3, 0, 0, 0);
        acc4 = __builtin_amdgcn_mfma_f32_16x16x32_bf16(af, ones, acc4, 0, 0, 0);

        tbuf[(t + 1) & 1][tid] = nx;              // write-late
    }
#undef PEL

    // acc4: every column holds the row-sum; C rows = q*4 + reg.
    int ic = rb * 64 + w * 16 + q * 4;
    if (r == 0) {
        #pragma unroll
        for (int reg = 0; reg < 4; ++reg)
            lpart[(size_t)g * NN + ic + reg] = acc4[reg];
    }

    size_t ob = (size_t)g * (size_t)(NN * F);
    #pragma unroll
    for (int reg = 0; reg < 4; ++reg) {
        size_t ro = ob + (size_t)(ic + reg) * F + r;
        Opart[ro]      = acc0[reg];
        Opart[ro + 16] = acc1[reg];
        Opart[ro + 32] = acc2[reg];
        Opart[ro + 48] = acc3[reg];
    }
}

// Kernel D: out = elu( (sum_g Opart) / (sum_g lpart) )
__global__ __launch_bounds__(256) void k_reduce(const float* __restrict__ Opart,
        const float* __restrict__ lpart, float* __restrict__ out) {
    int idx = blockIdx.x * 256 + threadIdx.x;
    int i = idx >> 6;
    float o = 0.f, l = 0.f;
    #pragma unroll
    for (int g = 0; g < G; ++g) {
        o += Opart[(size_t)g * (NN * F) + idx];
        l += lpart[(size_t)g * NN + i];
    }
    float hp = o / l;
    out[idx] = hp > 0.f ? hp : __expf(hp) - 1.f;
}

extern "C" void kernel_launch(void* const* d_in, const int* in_sizes, int n_in,
                              void* d_out, int out_size, void* d_ws, size_t ws_size,
                              hipStream_t stream) {
    const float* h  = (const float*)d_in[0];
    const int* adj  = (const int*)d_in[1];
    const float* W  = (const float*)d_in[2];
    const float* a  = (const float*)d_in[3];
    float* out = (float*)d_out;

    char* ws = (char*)d_ws;
    const size_t OFF_WHTT = 0;                       // 1 MB fragment-order WhTt
    const size_t OFF_SRC  = (1u << 20);              // 32 KB
    const size_t OFF_DST  = OFF_SRC + (32u << 10);   // 32 KB
    const size_t OFF_LP   = OFF_DST + (32u << 10);   // 256 KB (G*NN*4)
    const size_t OFF_MASK = OFF_LP + (size_t)G * NN * 4;      // 8 MB bitmask
    const size_t OFF_OP   = OFF_MASK + (size_t)NN * (NN / 8); // 16 MB Opart

    short* WhTt  = (short*)(ws + OFF_WHTT);
    float* src   = (float*)(ws + OFF_SRC);
    float* dst2  = (float*)(ws + OFF_DST);
    float* lpart = (float*)(ws + OFF_LP);
    unsigned long long* maskg = (unsigned long long*)(ws + OFF_MASK);
    float* Opart = (float*)(ws + OFF_OP);

    // merged prep(2048 blocks) + mask(2048 blocks): independent halves
    // co-scheduled -> HBM-bound mask overlaps VALU-bound prep.
    k_fused0<<<NN / 4 + 2048, 256, 0, stream>>>(h, W, a, adj, WhTt, src, dst2, maskg);
    k_attn<<<(NN / 64) * G, 256, 0, stream>>>((const unsigned*)maskg,
                                              (const short8*)WhTt, src, dst2,
                                              Opart, lpart);
    k_reduce<<<(NN * F) / 256, 256, 0, stream>>>(Opart, lpart, out);
}

// Round 15
// 90.254 us; speedup vs baseline: 1.6244x; 1.1337x over previous
//
#include <hip/hip_runtime.h>
#include <hip/hip_bf16.h>

#define NN 8192
#define F 64
#define ALPHA 0.2f
#define L2E 1.44269504f
#define DBOUND 16.0f
#define G 8
#define COLS (NN / G)        // 1024
#define NSTEPS (COLS / 32)   // 32

typedef __attribute__((ext_vector_type(8))) short short8;
typedef __attribute__((ext_vector_type(4))) float f32x4;
typedef __attribute__((ext_vector_type(4))) int i32x4;

__device__ __forceinline__ unsigned fb(float x) {
    return __builtin_bit_cast(unsigned, x);
}
__device__ __forceinline__ short f2bf(float x) {
    union { float f; unsigned u; } v; v.f = x;
    unsigned r = v.u + 0x7FFF + ((v.u >> 16) & 1);
    return (short)(r >> 16);
}

// Kernel A: Wh = h @ W^T (fp32); WhTt written DIRECTLY in MFMA-fragment
// order (R14-verified index algebra); src = Wh@a1; dst2 = (Wh@a2)*log2e.
__global__ __launch_bounds__(256) void k_prep(const float* __restrict__ h,
        const float* __restrict__ W, const float* __restrict__ a,
        short* __restrict__ WhTt, float* __restrict__ src, float* __restrict__ dst2) {
    __shared__ float Wl[F][F + 1];
    __shared__ short shT[F][4];
    int tid = threadIdx.x;
    for (int m = 0; m < 4; ++m) {
        int idx = m * 1024 + tid * 4;
        float4 v = *(const float4*)&W[idx];
        int row = idx >> 6, col = idx & 63;
        Wl[row][col] = v.x; Wl[row][col + 1] = v.y;
        Wl[row][col + 2] = v.z; Wl[row][col + 3] = v.w;
    }
    __syncthreads();
    int w = tid >> 6, lane = tid & 63;
    int i = blockIdx.x * 4 + w;
    const float* hrow = &h[(size_t)i * F];
    float wh = 0.f;
    #pragma unroll
    for (int k = 0; k < F; k += 4) {
        float4 hv = *(const float4*)&hrow[k];
        wh += hv.x * Wl[lane][k] + hv.y * Wl[lane][k + 1]
            + hv.z * Wl[lane][k + 2] + hv.w * Wl[lane][k + 3];
    }
    shT[lane][w] = f2bf(wh);
    float s1 = wh * a[lane];
    float s2 = wh * a[F + lane];
    #pragma unroll
    for (int off = 32; off; off >>= 1) {
        s1 += __shfl_xor(s1, off);
        s2 += __shfl_xor(s2, off);
    }
    if (lane == 0) { src[i] = s1; dst2[i] = s2 * L2E; }
    __syncthreads();
    if (tid < F) {
        int f = tid;
        int b = blockIdx.x;
        int t = b >> 3;
        int off = (b * 4) & 31;
        size_t addr = (((size_t)(t * 4 + (f >> 4)) * 64
                       + (off >> 3) * 16 + (f & 15)) << 3) + (off & 7);
        short4 v = make_short4(shT[f][0], shT[f][1], shT[f][2], shT[f][3]);
        *(short4*)&WhTt[addr] = v;
    }
}

// Kernel M: compress adj (256 MB int32) -> bitmask (8 MB). STANDALONE and
// pure (every coupling attempt degraded the stream). 6.2 TB/s measured.
__global__ __launch_bounds__(256) void k_mask(const int* __restrict__ adj,
                                              unsigned long long* __restrict__ mg) {
    int w = threadIdx.x >> 6, l = threadIdx.x & 63;
    int gw = blockIdx.x * 4 + w;              // global wave id
    const int NW = 2048 * 4;                  // total waves
    const int NCH = (NN * NN) / 256;          // 262144 chunks of 256 ints (1 KB)
    int sh = 4 * (l & 15);
    #pragma unroll 4
    for (int c = gw; c < NCH; c += NW) {
        size_t base = (size_t)c * 256;
        i32x4 a = __builtin_nontemporal_load((const i32x4*)(adj + base) + l);
        unsigned n = (a.x > 0 ? 1u : 0u) | (a.y > 0 ? 2u : 0u)
                   | (a.z > 0 ? 4u : 0u) | (a.w > 0 ? 8u : 0u);
        unsigned long long v = (unsigned long long)n << sh;
        v |= __shfl_xor(v, 1);
        v |= __shfl_xor(v, 2);
        v |= __shfl_xor(v, 4);
        v |= __shfl_xor(v, 8);
        if ((l & 15) == 0)
            mg[base / 64 + (l >> 4)] = v;
    }
}

// Kernel B: fused masked-softmax attention, NO LDS tile staging, NO loop
// barriers: B-fragments direct from L2 (fragment-order WhTt, 4 wave-linear
// 1KB bursts/step), register double-buffered. mask+dst2 in LDS (read-only).
__global__ __launch_bounds__(256, 4) void k_attn(const unsigned* __restrict__ maskg,
        const short8* __restrict__ WhTt, const float* __restrict__ src,
        const float* __restrict__ dst2,
        float* __restrict__ Opart, float* __restrict__ lpart) {
    __shared__ unsigned mlds[64][33];     // 64 rows x 32 mask dwords (+1 pad)
    __shared__ float dlds[COLS];          // dst2 slice

    int rb = blockIdx.x / G;
    int g  = blockIdx.x % G;
    int jbase = g * COLS;
    int tid = threadIdx.x;

    for (int idx = tid; idx < 64 * (COLS / 32); idx += 256) {
        int rr = idx >> 5, cc = idx & 31;
        mlds[rr][cc] = maskg[(size_t)(rb * 64 + rr) * (NN / 32) + (jbase >> 5) + cc];
    }
    for (int idx = tid; idx < COLS; idx += 256)
        dlds[idx] = dst2[jbase + idx];
    __syncthreads();

    int w = tid >> 6, lane = tid & 63;
    int r = lane & 15, q = lane >> 4;
    int qs = q * 8;
    int i = rb * 64 + w * 16 + r;

    float srcv = src[i];
    float sM = srcv + DBOUND;
    float Mi = fmaxf(sM, ALPHA * sM);
    float sL  = srcv * L2E;
    float MiL = Mi * L2E;
    float C1 = sL - MiL;
    float C2 = fmaf(sL, ALPHA, -MiL);

    f32x4 acc0{}, acc1{}, acc2{}, acc3{}, acc4{};
    short8 ones;
    #pragma unroll
    for (int k = 0; k < 8; ++k) ones[k] = (short)0x3F80;  // bf16 1.0

    const unsigned* mrow = &mlds[w * 16 + r][0];

#define LDB(tt, B0, B1, B2, B3) { \
    const short8* bp = WhTt + (size_t)(g * 32 + (tt)) * 256; \
    B0 = bp[lane]; B1 = bp[64 + lane]; B2 = bp[128 + lane]; B3 = bp[192 + lane]; }

#define PEL(dv, bit, eo) { \
    float t1 = (dv) + C1; \
    float t2 = fmaf((dv), ALPHA, C2); \
    float e = __builtin_amdgcn_exp2f(fmaxf(t1, t2)); \
    eo = (bit) ? e : 0.0f; }

    short8 cb0, cb1, cb2, cb3, nb0, nb1, nb2, nb3;
    LDB(0, cb0, cb1, cb2, cb3)

    #pragma unroll 4
    for (int t = 0; t < NSTEPS; ++t) {
        int tn = (t + 1 < NSTEPS) ? t + 1 : t;
        LDB(tn, nb0, nb1, nb2, nb3)           // in flight over this step

        unsigned m8 = (mrow[t] >> qs) & 0xffu;
        float4 d0 = *(const float4*)&dlds[t * 32 + qs];
        float4 d1 = *(const float4*)&dlds[t * 32 + qs + 4];

        float e0, e1, e2, e3, e4, e5, e6, e7;
        PEL(d0.x, (m8 & 1u),   e0) PEL(d0.y, (m8 & 2u),   e1)
        PEL(d0.z, (m8 & 4u),   e2) PEL(d0.w, (m8 & 8u),   e3)
        PEL(d1.x, (m8 & 16u),  e4) PEL(d1.y, (m8 & 32u),  e5)
        PEL(d1.z, (m8 & 64u),  e6) PEL(d1.w, (m8 & 128u), e7)

        unsigned w0 = __builtin_amdgcn_perm(fb(e1), fb(e0), 0x07060302u);
        unsigned w1 = __builtin_amdgcn_perm(fb(e3), fb(e2), 0x07060302u);
        unsigned w2 = __builtin_amdgcn_perm(fb(e5), fb(e4), 0x07060302u);
        unsigned w3 = __builtin_amdgcn_perm(fb(e7), fb(e6), 0x07060302u);
        short8 af = __builtin_bit_cast(short8, make_uint4(w0, w1, w2, w3));

        acc0 = __builtin_amdgcn_mfma_f32_16x16x32_bf16(af, cb0, acc0, 0, 0, 0);
        acc1 = __builtin_amdgcn_mfma_f32_16x16x32_bf16(af, cb1, acc1, 0, 0, 0);
        acc2 = __builtin_amdgcn_mfma_f32_16x16x32_bf16(af, cb2, acc2, 0, 0, 0);
        acc3 = __builtin_amdgcn_mfma_f32_16x16x32_bf16(af, cb3, acc3, 0, 0, 0);
        acc4 = __builtin_amdgcn_mfma_f32_16x16x32_bf16(af, ones, acc4, 0, 0, 0);

        cb0 = nb0; cb1 = nb1; cb2 = nb2; cb3 = nb3;
    }
#undef PEL
#undef LDB

    // acc4: every column holds the row-sum; C rows = q*4 + reg.
    int ic = rb * 64 + w * 16 + q * 4;
    if (r == 0) {
        #pragma unroll
        for (int reg = 0; reg < 4; ++reg)
            lpart[(size_t)g * NN + ic + reg] = acc4[reg];
    }

    size_t ob = (size_t)g * (size_t)(NN * F);
    #pragma unroll
    for (int reg = 0; reg < 4; ++reg) {
        size_t ro = ob + (size_t)(ic + reg) * F + r;
        Opart[ro]      = acc0[reg];
        Opart[ro + 16] = acc1[reg];
        Opart[ro + 32] = acc2[reg];
        Opart[ro + 48] = acc3[reg];
    }
}

// Kernel D: out = elu( (sum_g Opart) / (sum_g lpart) )
__global__ __launch_bounds__(256) void k_reduce(const float* __restrict__ Opart,
        const float* __restrict__ lpart, float* __restrict__ out) {
    int idx = blockIdx.x * 256 + threadIdx.x;
    int i = idx >> 6;
    float o = 0.f, l = 0.f;
    #pragma unroll
    for (int g = 0; g < G; ++g) {
        o += Opart[(size_t)g * (NN * F) + idx];
        l += lpart[(size_t)g * NN + i];
    }
    float hp = o / l;
    out[idx] = hp > 0.f ? hp : __expf(hp) - 1.f;
}

extern "C" void kernel_launch(void* const* d_in, const int* in_sizes, int n_in,
                              void* d_out, int out_size, void* d_ws, size_t ws_size,
                              hipStream_t stream) {
    const float* h  = (const float*)d_in[0];
    const int* adj  = (const int*)d_in[1];
    const float* W  = (const float*)d_in[2];
    const float* a  = (const float*)d_in[3];
    float* out = (float*)d_out;

    char* ws = (char*)d_ws;
    const size_t OFF_WHTT = 0;                       // 1 MB fragment-order WhTt
    const size_t OFF_SRC  = (1u << 20);              // 32 KB
    const size_t OFF_DST  = OFF_SRC + (32u << 10);   // 32 KB
    const size_t OFF_LP   = OFF_DST + (32u << 10);   // 256 KB (G*NN*4)
    const size_t OFF_MASK = OFF_LP + (size_t)G * NN * 4;      // 8 MB bitmask
    const size_t OFF_OP   = OFF_MASK + (size_t)NN * (NN / 8); // 16 MB Opart

    short* WhTt  = (short*)(ws + OFF_WHTT);
    float* src   = (float*)(ws + OFF_SRC);
    float* dst2  = (float*)(ws + OFF_DST);
    float* lpart = (float*)(ws + OFF_LP);
    unsigned long long* maskg = (unsigned long long*)(ws + OFF_MASK);
    float* Opart = (float*)(ws + OFF_OP);

    k_mask<<<2048, 256, 0, stream>>>(adj, maskg);
    k_prep<<<NN / 4, 256, 0, stream>>>(h, W, a, WhTt, src, dst2);
    k_attn<<<(NN / 64) * G, 256, 0, stream>>>((const unsigned*)maskg,
                                              (const short8*)WhTt, src, dst2,
                                              Opart, lpart);
    k_reduce<<<(NN * F) / 256, 256, 0, stream>>>(Opart, lpart, out);
}